// Round 7
// baseline (508.380 us; speedup 1.0000x reference)
//
#include <hip/hip_runtime.h>
#include <hip/hip_bf16.h>

#define BB 2
#define SS 4096
#define DD 1024
#define HH 16
#define WW 256
#define FF 4096
#define HDIM 64
#define NBLK (SS / WW)       /* 16 */
#define MROWS (BB * SS)      /* 8192 */

typedef short bfrag8 __attribute__((ext_vector_type(8)));
typedef float floatx4 __attribute__((ext_vector_type(4)));

__device__ __forceinline__ float bf2f(ushort u) {
    union { uint i; float f; } c; c.i = ((uint)u) << 16; return c.f;
}
__device__ __forceinline__ ushort f2bf(float f) {
    union { float f; uint i; } c; c.f = f;
    uint r = (c.i + 0x7FFFu + ((c.i >> 16) & 1u)) >> 16;
    return (ushort)r;
}
// gelu(tanh approx) == x * sigmoid(2z), z = 0.79788456(x + 0.044715 x^3)
__device__ __forceinline__ float gelu_fast(float x) {
    float z2 = 1.5957691216057308f * x * (1.f + 0.044715f * x * x); // 2z
    return x / (1.f + __expf(-z2));
}

// async global->LDS, 16B per lane. LDS dest must be contiguous in lane order.
__device__ __forceinline__ void gload_lds16(const ushort* g, ushort* l) {
    __builtin_amdgcn_global_load_lds(
        (const __attribute__((address_space(1))) void*)g,
        (__attribute__((address_space(3))) void*)l, 16, 0, 0);
}

// ---------------------------------------------------------------------------
// f32 -> bf16 bulk convert (grid * 1024 elements)
// ---------------------------------------------------------------------------
__global__ __launch_bounds__(256) void cvt_f32_bf16(
    const float* __restrict__ in, ushort* __restrict__ out)
{
    size_t i = ((size_t)blockIdx.x * 256 + threadIdx.x) * 4;
    float4 v = *(const float4*)(in + i);
    union { ushort u[4]; uint2 d; } t;
    t.u[0] = f2bf(v.x); t.u[1] = f2bf(v.y);
    t.u[2] = f2bf(v.z); t.u[3] = f2bf(v.w);
    *(uint2*)(out + i) = t.d;
}

// ---------------------------------------------------------------------------
// Fused transpose-convert of ALL weights: f32 [K][N] -> bf16 [N][K].
// grid = (128, 32, 6); z selects the weight. 32x32 LDS tiles.
// ---------------------------------------------------------------------------
__global__ __launch_bounds__(256) void cvt_transpose_all(
    const float* __restrict__ Wq, const float* __restrict__ Wk,
    const float* __restrict__ Wv, const float* __restrict__ Wo,
    const float* __restrict__ W1, const float* __restrict__ W2,
    ushort* __restrict__ WqkvT, ushort* __restrict__ WoT,
    ushort* __restrict__ W1t, ushort* __restrict__ W2t)
{
    __shared__ ushort sT[32][33];
    const int z = blockIdx.z;
    const float* in; ushort* out; int K, N, n0, k0;
    if (z < 4) {
        if (blockIdx.x >= 32) return;
        in  = (z == 0) ? Wq : (z == 1) ? Wk : (z == 2) ? Wv : Wo;
        out = (z < 3) ? WqkvT + (size_t)z * 1024 * 1024 : WoT;
        K = 1024; N = 1024;
        n0 = blockIdx.x * 32; k0 = blockIdx.y * 32;
    } else if (z == 4) {
        in = W1; out = W1t; K = 1024; N = 4096;
        n0 = blockIdx.x * 32; k0 = blockIdx.y * 32;
    } else {
        in = W2; out = W2t; K = 4096; N = 1024;
        n0 = blockIdx.y * 32; k0 = blockIdx.x * 32;
    }

    const int r  = threadIdx.x >> 3;        // 0..31
    const int c4 = (threadIdx.x & 7) * 4;   // 0..28

    float4 v = *(const float4*)(in + (size_t)(k0 + r) * N + n0 + c4);
    sT[c4 + 0][r] = f2bf(v.x);
    sT[c4 + 1][r] = f2bf(v.y);
    sT[c4 + 2][r] = f2bf(v.z);
    sT[c4 + 3][r] = f2bf(v.w);
    __syncthreads();
    union { ushort u[4]; uint2 d; } t;
#pragma unroll
    for (int e = 0; e < 4; ++e) t.u[e] = sT[r][c4 + e];
    *(uint2*)(out + (size_t)(n0 + r) * K + k0 + c4) = t.d;
}

// ---------------------------------------------------------------------------
// GEMM: C[M,N] = A[M,K] @ B[K,N] + bias[N], Bt = B^T [N][K] bf16.
// 128x128 tile, BK=64, global_load_lds width-16 staging with XOR-swizzled
// k-granules. XCD-aware 1D grid. Operands swapped -> packed uint2 stores.
// ALL loop-invariant addressing hoisted out of the K-loop: LDS fragment
// offsets as ints (stay AS3), DMA src pointers bumped by += 64 per iter.
// ---------------------------------------------------------------------------
__global__ __launch_bounds__(256) void gemm_bt(
    const ushort* __restrict__ A, const ushort* __restrict__ Bt,
    const float* __restrict__ bias, ushort* __restrict__ C,
    int M, int N, int K, int act)
{
    __shared__ ushort sA[128 * 64];
    __shared__ ushort sB[128 * 64];

    const int tid  = threadIdx.x;
    const int nx   = N >> 7;
    const int nyg  = (M >> 7) >> 3;          // y-panels per XCD
    const int gid  = blockIdx.x;
    const int j    = gid >> 3;
    const int m0   = ((gid & 7) * nyg + j / nx) * 128;
    const int n0   = (j % nx) * 128;
    const int wave = tid >> 6;
    const int lane = tid & 63;
    const int wm   = (wave >> 1) * 64;
    const int wn   = (wave & 1) * 64;
    const int lrow = lane & 15;
    const int quad = lane >> 4;

    // ---- hoisted DMA descriptors (4 A + 4 B chunks of 16B per thread)
    const ushort* aSrc[4]; const ushort* bSrc[4];
    int dmaDst[4];
#pragma unroll
    for (int it = 0; it < 4; ++it) {
        int c    = it * 256 + tid;
        int row  = c >> 3;
        int scol = ((c ^ (row & 7)) & 7) << 3;
        aSrc[it] = A  + (size_t)(m0 + row) * K + scol;
        bSrc[it] = Bt + (size_t)(n0 + row) * K + scol;
        dmaDst[it] = c * 8;
    }
    // ---- hoisted fragment LDS offsets (loop-invariant: single-buffer)
    int aOff[2][4], bOff[2][4];
#pragma unroll
    for (int ks = 0; ks < 2; ++ks)
#pragma unroll
        for (int t = 0; t < 4; ++t) {
            int rowA = wm + t * 16 + lrow;
            int rowB = wn + t * 16 + lrow;
            int G    = ks * 4 + quad;
            aOff[ks][t] = rowA * 64 + (((G ^ rowA) & 7) << 3);
            bOff[ks][t] = rowB * 64 + (((G ^ rowB) & 7) << 3);
        }

    floatx4 acc[4][4];
#pragma unroll
    for (int i = 0; i < 4; ++i)
#pragma unroll
        for (int j2 = 0; j2 < 4; ++j2)
            acc[i][j2] = (floatx4){0.f, 0.f, 0.f, 0.f};

    for (int k0 = 0; k0 < K; k0 += 64) {
#pragma unroll
        for (int it = 0; it < 4; ++it) {
            gload_lds16(aSrc[it], &sA[dmaDst[it]]);
            gload_lds16(bSrc[it], &sB[dmaDst[it]]);
            aSrc[it] += 64; bSrc[it] += 64;
        }
        __syncthreads();

#pragma unroll
        for (int ks = 0; ks < 2; ++ks) {
            bfrag8 af[4], bfv[4];
#pragma unroll
            for (int mt = 0; mt < 4; ++mt)
                af[mt] = *(const bfrag8*)&sA[aOff[ks][mt]];
#pragma unroll
            for (int nt = 0; nt < 4; ++nt)
                bfv[nt] = *(const bfrag8*)&sB[bOff[ks][nt]];
#pragma unroll
            for (int mt = 0; mt < 4; ++mt)
#pragma unroll
                for (int nt = 0; nt < 4; ++nt)
                    acc[mt][nt] = __builtin_amdgcn_mfma_f32_16x16x32_bf16(
                        bfv[nt], af[mt], acc[mt][nt], 0, 0, 0);
        }
        __syncthreads();
    }

    // epilogue: m = m0+wm+mt*16+lrow (lane), n-chunk = n0+wn+nt*16+quad*4 (regs)
#pragma unroll
    for (int nt = 0; nt < 4; ++nt) {
        int nb = n0 + wn + nt * 16 + quad * 4;
        union { float4 v; float f[4]; } b4;
        b4.v = *(const float4*)(bias + nb);
#pragma unroll
        for (int mt = 0; mt < 4; ++mt) {
            int row = m0 + wm + mt * 16 + lrow;
            union { ushort u[4]; uint2 d; } t;
#pragma unroll
            for (int r = 0; r < 4; ++r) {
                float v = acc[mt][nt][r] + b4.f[r];
                if (act) v = gelu_fast(v);
                t.u[r] = f2bf(v);
            }
            *(uint2*)(C + (size_t)row * N + nb) = t.d;
        }
    }
}

// ---------------------------------------------------------------------------
// Fused QKV GEMM: A[8192][1024] @ [Wq|Wk|Wv] (Bt = [3072][1024]), BK=64,
// swizzled staging, XCD-aware 1D grid, hoisted addressing. cols [0,1024) ->
// qb; [1024,2048) -> kb (swapped-operand); [2048,3072) -> vT [b][h][dh][s].
// ---------------------------------------------------------------------------
__global__ __launch_bounds__(256) void gemm_qkv(
    const ushort* __restrict__ A, const ushort* __restrict__ Bt,
    const float* __restrict__ bq, const float* __restrict__ bk,
    const float* __restrict__ bv,
    ushort* __restrict__ qb, ushort* __restrict__ kb, ushort* __restrict__ vT)
{
    __shared__ ushort sA[128 * 64];
    __shared__ ushort sB[128 * 64];
    const int K = DD;

    const int tid  = threadIdx.x;
    const int nx   = 24, nyg = 8;
    const int gid  = blockIdx.x;
    const int j    = gid >> 3;
    const int m0   = ((gid & 7) * nyg + j / nx) * 128;
    const int n0   = (j % nx) * 128;
    const int wave = tid >> 6;
    const int lane = tid & 63;
    const int wm   = (wave >> 1) * 64;
    const int wn   = (wave & 1) * 64;
    const int lrow = lane & 15;
    const int quad = lane >> 4;
    const int sel  = n0 >> 10;               // block-uniform: 0=q 1=k 2=v

    const ushort* aSrc[4]; const ushort* bSrc[4];
    int dmaDst[4];
#pragma unroll
    for (int it = 0; it < 4; ++it) {
        int c    = it * 256 + tid;
        int row  = c >> 3;
        int scol = ((c ^ (row & 7)) & 7) << 3;
        aSrc[it] = A  + (size_t)(m0 + row) * K + scol;
        bSrc[it] = Bt + (size_t)(n0 + row) * K + scol;
        dmaDst[it] = c * 8;
    }
    int aOff[2][4], bOff[2][4];
#pragma unroll
    for (int ks = 0; ks < 2; ++ks)
#pragma unroll
        for (int t = 0; t < 4; ++t) {
            int rowA = wm + t * 16 + lrow;
            int rowB = wn + t * 16 + lrow;
            int G    = ks * 4 + quad;
            aOff[ks][t] = rowA * 64 + (((G ^ rowA) & 7) << 3);
            bOff[ks][t] = rowB * 64 + (((G ^ rowB) & 7) << 3);
        }

    floatx4 acc[4][4];
#pragma unroll
    for (int i = 0; i < 4; ++i)
#pragma unroll
        for (int j2 = 0; j2 < 4; ++j2)
            acc[i][j2] = (floatx4){0.f, 0.f, 0.f, 0.f};

    for (int k0 = 0; k0 < K; k0 += 64) {
#pragma unroll
        for (int it = 0; it < 4; ++it) {
            gload_lds16(aSrc[it], &sA[dmaDst[it]]);
            gload_lds16(bSrc[it], &sB[dmaDst[it]]);
            aSrc[it] += 64; bSrc[it] += 64;
        }
        __syncthreads();

#pragma unroll
        for (int ks = 0; ks < 2; ++ks) {
            bfrag8 af[4], bfv[4];
#pragma unroll
            for (int mt = 0; mt < 4; ++mt)
                af[mt] = *(const bfrag8*)&sA[aOff[ks][mt]];
#pragma unroll
            for (int nt = 0; nt < 4; ++nt)
                bfv[nt] = *(const bfrag8*)&sB[bOff[ks][nt]];
            if (sel < 2) {
#pragma unroll
                for (int mt = 0; mt < 4; ++mt)
#pragma unroll
                    for (int nt = 0; nt < 4; ++nt)
                        acc[mt][nt] = __builtin_amdgcn_mfma_f32_16x16x32_bf16(
                            bfv[nt], af[mt], acc[mt][nt], 0, 0, 0);
            } else {
#pragma unroll
                for (int mt = 0; mt < 4; ++mt)
#pragma unroll
                    for (int nt = 0; nt < 4; ++nt)
                        acc[mt][nt] = __builtin_amdgcn_mfma_f32_16x16x32_bf16(
                            af[mt], bfv[nt], acc[mt][nt], 0, 0, 0);
            }
        }
        __syncthreads();
    }

    if (sel < 2) {
        ushort* C = (sel == 0) ? qb : kb;
        const float* bias = (sel == 0) ? bq : bk;
        const int colbase = n0 + wn;
#pragma unroll
        for (int nt = 0; nt < 4; ++nt) {
            int nb = (colbase + nt * 16 + quad * 4) & 1023;
            union { float4 v; float f[4]; } b4;
            b4.v = *(const float4*)(bias + nb);
#pragma unroll
            for (int mt = 0; mt < 4; ++mt) {
                int row = m0 + wm + mt * 16 + lrow;
                union { ushort u[4]; uint2 d; } t;
#pragma unroll
                for (int r = 0; r < 4; ++r) t.u[r] = f2bf(acc[mt][nt][r] + b4.f[r]);
                *(uint2*)(C + (size_t)row * DD + nb) = t.d;
            }
        }
    } else {
        const int colbase = n0 + wn;
#pragma unroll
        for (int nt = 0; nt < 4; ++nt) {
            int cc = (colbase + nt * 16 + lrow) & 1023;
            int h = cc >> 6, dh = cc & 63;
            float bb = bv[cc];
#pragma unroll
            for (int mt = 0; mt < 4; ++mt) {
                int row0 = m0 + wm + mt * 16 + (quad << 2);
                int b = row0 >> 12, s = row0 & 4095;
                union { ushort u[4]; uint2 d; } t;
#pragma unroll
                for (int r = 0; r < 4; ++r) t.u[r] = f2bf(acc[mt][nt][r] + bb);
                *(uint2*)(vT + (size_t)(((b * HH + h) * HDIM + dh)) * SS + s) = t.d;
            }
        }
    }
}

// ---------------------------------------------------------------------------
// Barrier-free MFMA flash attention. One wave per block; block = (qt, h, b).
// S^T = K·Q^T -> online softmax -> P via swizzled LDS -> O^T += V^T·P^T
// (V^T straight from global vT). No __syncthreads.
// ---------------------------------------------------------------------------
__global__ __launch_bounds__(64, 2) void attn_flash(
    const ushort* __restrict__ q, const ushort* __restrict__ k,
    const ushort* __restrict__ vT, ushort* __restrict__ out)
{
    __shared__ ushort sP[64 * 72];

    const int qt = blockIdx.x, h = blockIdx.y, b = blockIdx.z;
    const int lane = threadIdx.x;
    const int c16  = lane & 15;
    const int quad = lane >> 4;
    const float CC = 0.18033688011112042f;   // (1/sqrt(64)) * log2(e)

    bfrag8 qf[4][2];
    {
        const size_t qbase = ((size_t)b * SS + qt * 64) * DD + h * HDIM;
#pragma unroll
        for (int nt = 0; nt < 4; ++nt)
#pragma unroll
            for (int ks = 0; ks < 2; ++ks)
                qf[nt][ks] = *(const bfrag8*)(q + qbase +
                    (size_t)(nt * 16 + c16) * DD + ks * 32 + quad * 8);
    }

    floatx4 oacc[4][4];
#pragma unroll
    for (int i = 0; i < 4; ++i)
#pragma unroll
        for (int j = 0; j < 4; ++j)
            oacc[i][j] = (floatx4){0.f, 0.f, 0.f, 0.f};
    float mrow[4], lsum[4];
#pragma unroll
    for (int i = 0; i < 4; ++i) { mrow[i] = -1e30f; lsum[i] = 0.f; }

    const int st0 = (qt - 4 > 0) ? qt - 4 : 0;
    const int st1 = (qt + 4 < 63) ? qt + 4 : 63;
    const size_t kb_b  = (size_t)b * SS * DD + h * HDIM;
    const size_t vT_b  = (size_t)((b * HH + h) * HDIM) * SS;

    for (int st = st0; st <= st1; ++st) {
        const int dlt = st - qt;

        floatx4 sacc[4][4];
#pragma unroll
        for (int i = 0; i < 4; ++i)
#pragma unroll
            for (int j = 0; j < 4; ++j)
                sacc[i][j] = (floatx4){0.f, 0.f, 0.f, 0.f};
#pragma unroll
        for (int ks = 0; ks < 2; ++ks) {
            bfrag8 kf[4];
#pragma unroll
            for (int mt = 0; mt < 4; ++mt)
                kf[mt] = *(const bfrag8*)(k + kb_b +
                    (size_t)(st * 64 + mt * 16 + c16) * DD + ks * 32 + quad * 8);
#pragma unroll
            for (int mt = 0; mt < 4; ++mt)
#pragma unroll
                for (int nt = 0; nt < 4; ++nt)
                    sacc[mt][nt] = __builtin_amdgcn_mfma_f32_16x16x32_bf16(
                        kf[mt], qf[nt][ks], sacc[mt][nt], 0, 0, 0);
        }

        if (dlt == 4 || dlt == -4) {
#pragma unroll
            for (int mt = 0; mt < 4; ++mt)
#pragma unroll
                for (int nt = 0; nt < 4; ++nt)
#pragma unroll
                    for (int r = 0; r < 4; ++r) {
                        int kl = mt * 16 + quad * 4 + r;
                        int ql = nt * 16 + c16;
                        bool ok = (dlt < 0) ? (kl >= ql) : (kl <= ql);
                        if (!ok) sacc[mt][nt][r] = -1e30f;
                    }
        }

        float pm[4];
#pragma unroll
        for (int nt = 0; nt < 4; ++nt) {
            float a0 = fmaxf(fmaxf(sacc[0][nt][0], sacc[0][nt][1]),
                             fmaxf(sacc[0][nt][2], sacc[0][nt][3]));
            float a1 = fmaxf(fmaxf(sacc[1][nt][0], sacc[1][nt][1]),
                             fmaxf(sacc[1][nt][2], sacc[1][nt][3]));
            float a2 = fmaxf(fmaxf(sacc[2][nt][0], sacc[2][nt][1]),
                             fmaxf(sacc[2][nt][2], sacc[2][nt][3]));
            float a3 = fmaxf(fmaxf(sacc[3][nt][0], sacc[3][nt][1]),
                             fmaxf(sacc[3][nt][2], sacc[3][nt][3]));
            pm[nt] = fmaxf(fmaxf(a0, a1), fmaxf(a2, a3));
            pm[nt] = fmaxf(pm[nt], __shfl_xor(pm[nt], 16, 64));
            pm[nt] = fmaxf(pm[nt], __shfl_xor(pm[nt], 32, 64));
        }
        float al[4];
#pragma unroll
        for (int nt = 0; nt < 4; ++nt) {
            float mn = fmaxf(mrow[nt], pm[nt]);
            al[nt] = exp2f((mrow[nt] - mn) * CC);
            mrow[nt] = mn;
        }
        float ps[4] = {0.f, 0.f, 0.f, 0.f};
#pragma unroll
        for (int mt = 0; mt < 4; ++mt)
#pragma unroll
            for (int nt = 0; nt < 4; ++nt)
#pragma unroll
                for (int r = 0; r < 4; ++r) {
                    float p = exp2f((sacc[mt][nt][r] - mrow[nt]) * CC);
                    sacc[mt][nt][r] = p;
                    ps[nt] += p;
                }
#pragma unroll
        for (int nt = 0; nt < 4; ++nt) {
            ps[nt] += __shfl_xor(ps[nt], 16, 64);
            ps[nt] += __shfl_xor(ps[nt], 32, 64);
            lsum[nt] = lsum[nt] * al[nt] + ps[nt];
        }

#pragma unroll
        for (int mt = 0; mt < 4; ++mt)
#pragma unroll
            for (int nt = 0; nt < 4; ++nt) {
                int row = nt * 16 + c16;
                int g   = (2 * mt + (quad >> 1)) ^ (row & 3);
                union { ushort u[4]; uint2 d; } t;
#pragma unroll
                for (int r = 0; r < 4; ++r) t.u[r] = f2bf(sacc[mt][nt][r]);
                *(uint2*)&sP[row * 72 + g * 8 + (quad & 1) * 4] = t.d;
            }

#pragma unroll
        for (int dt = 0; dt < 4; ++dt)
#pragma unroll
            for (int nq = 0; nq < 4; ++nq)
#pragma unroll
                for (int r = 0; r < 4; ++r)
                    oacc[dt][nq][r] *= al[nq];

#pragma unroll
        for (int ks = 0; ks < 2; ++ks) {
            bfrag8 vf[4], pf[4];
#pragma unroll
            for (int dt = 0; dt < 4; ++dt)
                vf[dt] = *(const bfrag8*)(vT + vT_b +
                    (size_t)(dt * 16 + c16) * SS + st * 64 + ks * 32 + quad * 8);
#pragma unroll
            for (int nq = 0; nq < 4; ++nq) {
                int row = nq * 16 + c16;
                int g   = (4 * ks + quad) ^ (row & 3);
                pf[nq] = *(const bfrag8*)&sP[row * 72 + g * 8];
            }
#pragma unroll
            for (int dt = 0; dt < 4; ++dt)
#pragma unroll
                for (int nq = 0; nq < 4; ++nq)
                    oacc[dt][nq] = __builtin_amdgcn_mfma_f32_16x16x32_bf16(
                        vf[dt], pf[nq], oacc[dt][nq], 0, 0, 0);
        }
    }

#pragma unroll
    for (int nq = 0; nq < 4; ++nq) {
        float inv = 1.f / lsum[nq];
        size_t rbase = ((size_t)b * SS + qt * 64 + nq * 16 + c16) * DD + h * HDIM;
#pragma unroll
        for (int dt = 0; dt < 4; ++dt) {
            union { ushort u[4]; uint2 d; } t;
#pragma unroll
            for (int r = 0; r < 4; ++r) t.u[r] = f2bf(oacc[dt][nq][r] * inv);
            *(uint2*)(out + rbase + dt * 16 + quad * 4) = t.d;
        }
    }
}

// ---------------------------------------------------------------------------
// out = LayerNorm(a + res) * g + b    (one block per row of D=1024)
// ---------------------------------------------------------------------------
__device__ __forceinline__ float ldv(const float* p)  { return *p; }
__device__ __forceinline__ float ldv(const ushort* p) { return bf2f(*p); }
__device__ __forceinline__ void  stv(float* p, float v)  { *p = v; }
__device__ __forceinline__ void  stv(ushort* p, float v) { *p = f2bf(v); }

template <typename RT, typename OT>
__global__ __launch_bounds__(256) void add_ln(
    const ushort* __restrict__ a, const RT* __restrict__ res,
    const float* __restrict__ g, const float* __restrict__ bb,
    OT* __restrict__ out)
{
    const int row = blockIdx.x;
    const int tid = threadIdx.x;
    const size_t base = (size_t)row * DD + tid * 4;

    float x[4];
    float s1 = 0.f, s2 = 0.f;
#pragma unroll
    for (int e = 0; e < 4; ++e) {
        x[e] = bf2f(a[base + e]) + ldv(res + base + e);
        s1 += x[e];
        s2 += x[e] * x[e];
    }
#pragma unroll
    for (int off = 32; off > 0; off >>= 1) {
        s1 += __shfl_down(s1, off, 64);
        s2 += __shfl_down(s2, off, 64);
    }
    __shared__ float r1[4], r2[4];
    const int wave = tid >> 6, lane = tid & 63;
    if (lane == 0) { r1[wave] = s1; r2[wave] = s2; }
    __syncthreads();
    float t1 = r1[0] + r1[1] + r1[2] + r1[3];
    float t2 = r2[0] + r2[1] + r2[2] + r2[3];
    float mu  = t1 * (1.f / DD);
    float var = t2 * (1.f / DD) - mu * mu;
    float rs  = rsqrtf(var + 1e-5f);

#pragma unroll
    for (int e = 0; e < 4; ++e) {
        int col = tid * 4 + e;
        float y = (x[e] - mu) * rs * g[col] + bb[col];
        stv(out + base + e, y);
    }
}

// ---------------------------------------------------------------------------
extern "C" void kernel_launch(void* const* d_in, const int* in_sizes, int n_in,
                              void* d_out, int out_size, void* d_ws, size_t ws_size,
                              hipStream_t stream)
{
    (void)in_sizes; (void)n_in; (void)out_size; (void)ws_size;

    const float* x  = (const float*)d_in[0];
    const float* Wq = (const float*)d_in[1];
    const float* bq = (const float*)d_in[2];
    const float* Wk = (const float*)d_in[3];
    const float* bk = (const float*)d_in[4];
    const float* Wv = (const float*)d_in[5];
    const float* bv = (const float*)d_in[6];
    const float* Wo = (const float*)d_in[7];
    const float* bo = (const float*)d_in[8];
    const float* g1 = (const float*)d_in[9];
    const float* b1 = (const float*)d_in[10];
    const float* W1 = (const float*)d_in[11];
    const float* c1 = (const float*)d_in[12];
    const float* W2 = (const float*)d_in[13];
    const float* c2 = (const float*)d_in[14];
    const float* g2 = (const float*)d_in[15];
    const float* b2 = (const float*)d_in[16];
    float* outp = (float*)d_out;

    char* ws = (char*)d_ws;
    const size_t MB = 1024 * 1024;
    ushort* WqkvT = (ushort*)(ws);            // [  0,  6): Wq^T|Wk^T|Wv^T
    ushort* WoT = (ushort*)(ws + 6  * MB);    // [  6,  8)
    ushort* W1t = (ushort*)(ws + 8  * MB);    // [  8, 16)
    ushort* W2t = (ushort*)(ws + 16 * MB);    // [ 16, 24)
    ushort* xb  = (ushort*)(ws + 24 * MB);    // [ 24, 40)
    ushort* qb  = (ushort*)(ws + 40 * MB);    // [ 40, 56)
    ushort* kb  = (ushort*)(ws + 56 * MB);    // [ 56, 72)
    ushort* vT  = (ushort*)(ws + 72 * MB);    // [ 72, 88)  [b][h][64][4096]
    ushort* att = (ushort*)(ws + 88 * MB);    // [ 88,104)
    ushort* aproj = qb;
    ushort* hbuf  = att;
    ushort* m1  = (ushort*)(ws + 24 * MB);    // [ 24, 88)
    ushort* fbuf = (ushort*)(ws + 104 * MB);  // [104,120)

    dim3 blk(256, 1, 1);
    dim3 gD1((DD / 128) * (MROWS / 128), 1, 1);       // 512 blocks, 1D
    dim3 gQKV1((3 * DD / 128) * (MROWS / 128), 1, 1); // 1536 blocks
    dim3 gF1((FF / 128) * (MROWS / 128), 1, 1);       // 2048 blocks
    dim3 ga(SS / 64, HH, BB);
    dim3 gl(MROWS, 1, 1);

    hipLaunchKernelGGL(cvt_transpose_all, dim3(128, 32, 6), blk, 0, stream,
                       Wq, Wk, Wv, Wo, W1, W2, WqkvT, WoT, W1t, W2t);
    hipLaunchKernelGGL(cvt_f32_bf16, dim3(8192), blk, 0, stream, x, xb);

    hipLaunchKernelGGL(gemm_qkv, gQKV1, blk, 0, stream, xb, WqkvT, bq, bk, bv, qb, kb, vT);

    hipLaunchKernelGGL(attn_flash, ga, dim3(64, 1, 1), 0, stream, qb, kb, vT, att);

    hipLaunchKernelGGL(gemm_bt, gD1, blk, 0, stream, att, WoT, bo, aproj, MROWS, DD, DD, 0);
    hipLaunchKernelGGL((add_ln<float, ushort>), gl, blk, 0, stream, aproj, x, g1, b1, hbuf);

    hipLaunchKernelGGL(gemm_bt, gF1, blk, 0, stream, hbuf, W1t, c1, m1, MROWS, FF, DD, 1);
    hipLaunchKernelGGL(gemm_bt, gD1, blk, 0, stream, m1, W2t, c2, fbuf, MROWS, DD, FF, 0);
    hipLaunchKernelGGL((add_ln<ushort, float>), gl, blk, 0, stream, fbuf, hbuf, g2, b2, outp);
}